// Round 12
// baseline (656.402 us; speedup 1.0000x reference)
//
#include <hip/hip_runtime.h>
#include <stdint.h>

#define NN 100000
#define EE 1600000
#define DD 256

typedef __bf16 bf16;
typedef __attribute__((ext_vector_type(8))) __bf16 bf16x8;
typedef __attribute__((ext_vector_type(4))) float f32x4;
typedef __attribute__((ext_vector_type(4))) unsigned int u32x4;
typedef __attribute__((ext_vector_type(8))) unsigned short u16x8;

typedef __attribute__((address_space(1))) const unsigned int g_u32c;
typedef __attribute__((address_space(3))) unsigned int lds_u32;

__device__ __forceinline__ float bflo(unsigned int u) {
    union { unsigned int u; float f; } x; x.u = u << 16; return x.f;
}
__device__ __forceinline__ float bfhi(unsigned int u) {
    union { unsigned int u; float f; } x; x.u = u & 0xFFFF0000u; return x.f;
}
__device__ __forceinline__ unsigned short f2bf(float f) {
    return __builtin_bit_cast(unsigned short, (__bf16)f);
}

// ---------------------------------------------------------------------------
// CSR build (cs only — edge weights folded into pre/post dinv scaling)
// ---------------------------------------------------------------------------
__global__ void count_deg_k(const int* __restrict__ dst, int* __restrict__ cnt) {
    int e = blockIdx.x * 256 + threadIdx.x;
    if (e < EE) atomicAdd(&cnt[dst[e]], 1);
}
__global__ __launch_bounds__(256) void scan_blk_k(const int* __restrict__ cnt,
                                                  int* __restrict__ part,
                                                  int* __restrict__ bsum,
                                                  float* __restrict__ dinv) {
    __shared__ int buf[256];
    int i = blockIdx.x * 256 + threadIdx.x;
    int v = 0;
    if (i < NN) { v = cnt[i] + 1; dinv[i] = rsqrtf((float)v); }   // +1 self-loop
    buf[threadIdx.x] = v;
    __syncthreads();
    for (int off = 1; off < 256; off <<= 1) {
        int t = (threadIdx.x >= off) ? buf[threadIdx.x - off] : 0;
        __syncthreads();
        buf[threadIdx.x] += t;
        __syncthreads();
    }
    if (i < NN) part[i] = buf[threadIdx.x];
    if (threadIdx.x == 255) bsum[blockIdx.x] = buf[255];
}
__global__ __launch_bounds__(512) void scan_top_k(const int* __restrict__ bsum,
                                                  int* __restrict__ bpre, int nb) {
    __shared__ int buf[512];
    int v = (threadIdx.x < (unsigned)nb) ? bsum[threadIdx.x] : 0;
    buf[threadIdx.x] = v;
    __syncthreads();
    for (int off = 1; off < 512; off <<= 1) {
        int t = (threadIdx.x >= off) ? buf[threadIdx.x - off] : 0;
        __syncthreads();
        buf[threadIdx.x] += t;
        __syncthreads();
    }
    if (threadIdx.x < (unsigned)nb) bpre[threadIdx.x] = buf[threadIdx.x] - v;
}
__global__ void scan_fin_k(const int* __restrict__ part, const int* __restrict__ bpre,
                           const int* __restrict__ cnt,
                           int* __restrict__ offs, int* __restrict__ cur,
                           int* __restrict__ cs) {
    int i = blockIdx.x * 256 + threadIdx.x;
    if (i >= NN) return;
    int o1 = part[i] + bpre[blockIdx.x];
    offs[i + 1] = o1;
    if (i == 0) offs[0] = 0;
    int o = o1 - (cnt[i] + 1);
    cs[o] = i;                 // self-loop (dinv^2 emerges from pre+post scaling)
    cur[i] = o + 1;
}
// Dst-partitioned fill (R11-proven): part p = bid&7 -> one XCD under round-robin
// dispatch; cs/cur lines of one dst-range written from one XCD's L2.
#define NSUB 128
__global__ __launch_bounds__(256) void fill_csr_k(
    const int* __restrict__ src, const int* __restrict__ dst,
    int* __restrict__ cur, int* __restrict__ cs) {
    int bid = blockIdx.x;
    int prt = bid & 7;
    int sub = bid >> 3;
    int lo = prt * (NN >> 3);
    int hi = (prt == 7) ? NN : lo + (NN >> 3);
    const int per = EE / NSUB;
    int e0 = sub * per;
    int e1 = (sub == NSUB - 1) ? EE : e0 + per;
    for (int e = e0 + threadIdx.x; e < e1; e += 256) {
        int d = dst[e];
        if (d >= lo && d < hi) {
            int s = src[e];
            int pos = atomicAdd(&cur[d], 1);
            cs[pos] = s;
        }
    }
}

// ---------------------------------------------------------------------------
// prep: Wt[n][k] = (bf16)W[k][n] for 3 weights (blocks 0..191) + mask probe (192)
// ---------------------------------------------------------------------------
__global__ __launch_bounds__(256) void prep_k(
    const float* __restrict__ W0, const float* __restrict__ W1, const float* __restrict__ W2,
    bf16* __restrict__ T0, bf16* __restrict__ T1, bf16* __restrict__ T2,
    const unsigned int* __restrict__ m, int* __restrict__ flag) {
    int b = blockIdx.x;
    if (b == 192) {
        if (threadIdx.x < 64) {
            unsigned int v = m[threadIdx.x];
            int bad = (v > 1u && v != 0x3F800000u) ? 1 : 0;
            unsigned long long bl = __ballot(bad);
            if (threadIdx.x == 0) *flag = (bl != 0ull) ? 1 : 0;
        }
        return;
    }
    const float* W = b < 64 ? W0 : (b < 128 ? W1 : W2);
    bf16*       T  = b < 64 ? T0 : (b < 128 ? T1 : T2);
    int bb = b & 63;
    __shared__ float tile[32][33];
    int bx = bb & 7, by = bb >> 3;
    int tx = threadIdx.x & 31, ty = threadIdx.x >> 5;
    #pragma unroll
    for (int r = 0; r < 32; r += 8)
        tile[ty + r][tx] = W[(size_t)(by * 32 + ty + r) * DD + bx * 32 + tx];
    __syncthreads();
    #pragma unroll
    for (int r = 0; r < 32; r += 8)
        T[(size_t)(bx * 32 + ty + r) * DD + by * 32 + tx] = (bf16)tile[tx][ty + r];
}

// ---------------------------------------------------------------------------
// bf16 MFMA GEMM, full-N blocks: out[M,256] = A[M,256] @ W (Wt[n][k]).
// BM=128, BN=256 (whole width -> A read ONCE), BK=64. 512 thr = 8 waves
// (2m x 4n), 4x4 16x16x32 frags/wave (R8-proven register shape).
// LDS 48KB: As 128x64 (16KB), Bs 256x64 (32KB); linear layout.
// F32A=1: A is fp32 (omega) — reg-staged cvt into As (fuses the cvt pass).
// Swapped-operand MFMA -> 4 consecutive output cols/lane -> vector epilogue.
// EPI 1: +bias, relu, dropout(mask), *dinv[row] -> bf16.
// EPI 2: +bias, *z -> fp32 nt (final output).
// ---------------------------------------------------------------------------
template <int ID, int EPI, int F32A>
__global__ __launch_bounds__(512, 2) void gemm_k(
    const void* __restrict__ Ap, const bf16* __restrict__ Wt,
    const float* __restrict__ bias, const void* __restrict__ mask,
    const int* __restrict__ flagp, const float* __restrict__ z,
    const float* __restrict__ dinv, void* __restrict__ outp) {
    __shared__ __align__(16) bf16 As[128 * 64];
    __shared__ __align__(16) bf16 Bs[256 * 64];

    int m0 = blockIdx.x * 128;
    if (m0 >= NN) return;
    int tid = threadIdx.x;
    int wid = tid >> 6, lane = tid & 63;
    int wm = wid >> 2, wn = wid & 3;
    int lr = lane & 15, lk = lane >> 4;

    f32x4 acc[4][4] = {};

    for (int k0 = 0; k0 < DD; k0 += 64) {
        // ---- stage A tile: 1024 16B chunks / 512 thr = 2 per thread ----
        if (F32A) {
            const float* Af = (const float*)Ap;
            #pragma unroll
            for (int i = 0; i < 2; i++) {
                int f = i * 512 + tid;
                int row = f >> 3;
                int c   = (f & 7) * 8;
                int gr = m0 + row; if (gr > NN - 1) gr = NN - 1;
                const float* sp = Af + (size_t)gr * DD + k0 + c;
                float4 v0 = *(const float4*)sp;
                float4 v1 = *(const float4*)(sp + 4);
                u16x8 o = { f2bf(v0.x), f2bf(v0.y), f2bf(v0.z), f2bf(v0.w),
                            f2bf(v1.x), f2bf(v1.y), f2bf(v1.z), f2bf(v1.w) };
                *(u16x8*)(As + row * 64 + c) = o;
            }
        } else {
            const bf16* Ab = (const bf16*)Ap;
            #pragma unroll
            for (int i = 0; i < 2; i++) {
                int f = i * 512 + tid;
                int row = f >> 3;
                int c   = (f & 7) * 8;
                int gr = m0 + row; if (gr > NN - 1) gr = NN - 1;
                __builtin_amdgcn_global_load_lds(
                    (g_u32c*)(Ab + (size_t)gr * DD + k0 + c),
                    (lds_u32*)(As + (size_t)f * 8), 16, 0, 0);
            }
        }
        // ---- stage B panel: 2048 chunks / 512 thr = 4 per thread ----
        #pragma unroll
        for (int i = 0; i < 4; i++) {
            int f = i * 512 + tid;
            int row = f >> 3;                 // n index 0..255
            int c   = (f & 7) * 8;
            __builtin_amdgcn_global_load_lds(
                (g_u32c*)(Wt + (size_t)row * DD + k0 + c),
                (lds_u32*)(Bs + (size_t)f * 8), 16, 0, 0);
        }
        __syncthreads();

        #pragma unroll
        for (int kk = 0; kk < 2; kk++) {
            bf16x8 af[4], bfr[4];
            #pragma unroll
            for (int mi = 0; mi < 4; mi++)
                af[mi] = *(const bf16x8*)(As + (wm * 64 + mi * 16 + lr) * 64 + kk * 32 + lk * 8);
            #pragma unroll
            for (int ni = 0; ni < 4; ni++)
                bfr[ni] = *(const bf16x8*)(Bs + (wn * 64 + ni * 16 + lr) * 64 + kk * 32 + lk * 8);
            #pragma unroll
            for (int mi = 0; mi < 4; mi++)
                #pragma unroll
                for (int ni = 0; ni < 4; ni++)
                    acc[mi][ni] = __builtin_amdgcn_mfma_f32_16x16x32_bf16(
                        bfr[ni], af[mi], acc[mi][ni], 0, 0, 0);   // swapped
        }
        __syncthreads();
    }

    int bm = (EPI == 1) ? *flagp : 0;
    #pragma unroll
    for (int mi = 0; mi < 4; mi++) {
        int gr = m0 + wm * 64 + mi * 16 + lr;          // row = lane&15
        if (gr >= NN) continue;
        float ds = (EPI == 1) ? dinv[gr] : 0.f;        // pre-scale for agg input
        #pragma unroll
        for (int ni = 0; ni < 4; ni++) {
            int gc = wn * 64 + ni * 16 + lk * 4;       // 4 consecutive cols
            size_t idx = (size_t)gr * DD + gc;
            float4 b4 = *(const float4*)(bias + gc);
            float v0 = acc[mi][ni][0] + b4.x;
            float v1 = acc[mi][ni][1] + b4.y;
            float v2 = acc[mi][ni][2] + b4.z;
            float v3 = acc[mi][ni][3] + b4.w;
            if (EPI == 1) {
                v0 = fmaxf(v0, 0.f); v1 = fmaxf(v1, 0.f);
                v2 = fmaxf(v2, 0.f); v3 = fmaxf(v3, 0.f);
                if (bm) {
                    uchar4 u = *(const uchar4*)((const unsigned char*)mask + idx);
                    v0 *= u.x ? 2.f : 0.f; v1 *= u.y ? 2.f : 0.f;
                    v2 *= u.z ? 2.f : 0.f; v3 *= u.w ? 2.f : 0.f;
                } else {
                    uint4 u = *(const uint4*)((const unsigned int*)mask + idx);
                    v0 *= u.x ? 2.f : 0.f; v1 *= u.y ? 2.f : 0.f;
                    v2 *= u.z ? 2.f : 0.f; v3 *= u.w ? 2.f : 0.f;
                }
                v0 *= ds; v1 *= ds; v2 *= ds; v3 *= ds;
                ushort4 o = { f2bf(v0), f2bf(v1), f2bf(v2), f2bf(v3) };
                *(ushort4*)((unsigned short*)outp + idx) = o;
            } else {
                f32x4 zz = __builtin_nontemporal_load((const f32x4*)(z + idx));
                f32x4 o = { v0 * zz.x, v1 * zz.y, v2 * zz.z, v3 * zz.w };
                __builtin_nontemporal_store(o, (f32x4*)((float*)outp + idx));
            }
        }
    }
}

// ---------------------------------------------------------------------------
// CSR gather, unit weights (rows pre-scaled): out[n,:] = dinv[n] * sum rows.
// One wave per node; 32 lanes x 16B per row, 2 rows per step (half-split).
// Depth-4 load pipeline, named rotating registers, static indices.
// ---------------------------------------------------------------------------
#define AGG_GET(J, UVAR, MVAR)                                                   \
    {                                                                            \
        int _i = 2 * (J) + half;                                                 \
        int _s = __shfl(sl, _i & 63);                                            \
        MVAR = (_i < nume) ? 1.f : 0.f;                                          \
        UVAR = *(const u32x4*)(tb + (((size_t)(unsigned)_s) << 9) + lcoff);      \
    }
#define AGG_FMA(UVAR, MVAR)                                                      \
    {                                                                            \
        acc[0] = fmaf(MVAR, bflo(UVAR.x), acc[0]);                               \
        acc[1] = fmaf(MVAR, bfhi(UVAR.x), acc[1]);                               \
        acc[2] = fmaf(MVAR, bflo(UVAR.y), acc[2]);                               \
        acc[3] = fmaf(MVAR, bfhi(UVAR.y), acc[3]);                               \
        acc[4] = fmaf(MVAR, bflo(UVAR.z), acc[4]);                               \
        acc[5] = fmaf(MVAR, bfhi(UVAR.z), acc[5]);                               \
        acc[6] = fmaf(MVAR, bflo(UVAR.w), acc[6]);                               \
        acc[7] = fmaf(MVAR, bfhi(UVAR.w), acc[7]);                               \
    }

__global__ __launch_bounds__(256) void agg_k(
    const bf16* __restrict__ t, const int* __restrict__ offs,
    const int* __restrict__ cs, const float* __restrict__ dinv,
    bf16* __restrict__ out) {
    int node = blockIdx.x * 4 + (threadIdx.x >> 6);
    if (node >= NN) return;
    int lane = threadIdx.x & 63;
    int half = lane >> 5;
    int lc = lane & 31;
    int beg = offs[node], end = offs[node + 1];

    float acc[8] = {};
    const char* tb = (const char*)t;
    size_t lcoff = (size_t)(lc << 4);

    for (int base = beg; base < end; base += 64) {
        int nume = min(64, end - base);
        int sl = 0;
        if (lane < nume) sl = __builtin_nontemporal_load(cs + base + lane);
        int nit = (nume + 1) >> 1;

        u32x4 ua, ub, uc, ud;
        float ma, mb, mc, md;
        AGG_GET(0, ua, ma);
        AGG_GET(1, ub, mb);
        AGG_GET(2, uc, mc);
        int j = 0;
        for (; j + 3 < nit; j += 4) {
            AGG_GET(j + 3, ud, md); AGG_FMA(ua, ma);
            AGG_GET(j + 4, ua, ma); AGG_FMA(ub, mb);
            AGG_GET(j + 5, ub, mb); AGG_FMA(uc, mc);
            AGG_GET(j + 6, uc, mc); AGG_FMA(ud, md);
        }
        int rem = nit - j;
        if (rem > 0) AGG_FMA(ua, ma);
        if (rem > 1) AGG_FMA(ub, mb);
        if (rem > 2) AGG_FMA(uc, mc);
    }

    float dn = dinv[node];
    #pragma unroll
    for (int i = 0; i < 8; i++) {
        acc[i] += __shfl_xor(acc[i], 32);
        acc[i] *= dn;
    }
    if (half == 0) {
        u16x8 o = { f2bf(acc[0]), f2bf(acc[1]), f2bf(acc[2]), f2bf(acc[3]),
                    f2bf(acc[4]), f2bf(acc[5]), f2bf(acc[6]), f2bf(acc[7]) };
        __builtin_nontemporal_store(o, (u16x8*)((unsigned short*)out + (size_t)node * DD + lc * 8));
    }
}

// ---------------------------------------------------------------------------
extern "C" void kernel_launch(void* const* d_in, const int* in_sizes, int n_in,
                              void* d_out, int out_size, void* d_ws, size_t ws_size,
                              hipStream_t stream) {
    const float* z     = (const float*)d_in[0];
    const float* omega = (const float*)d_in[1];
    const int*   eidx  = (const int*)d_in[2];
    const float* W_lin = (const float*)d_in[3];
    const float* b_lin = (const float*)d_in[4];
    const float* W_g1  = (const float*)d_in[5];
    const float* b_g1  = (const float*)d_in[6];
    const float* W_g2  = (const float*)d_in[7];
    const float* b_g2  = (const float*)d_in[8];
    const void*  mask1 = d_in[9];
    const void*  mask2 = d_in[10];

    const int* e_src = eidx;
    const int* e_dst = eidx + EE;

    char* p = (char*)d_ws;
    size_t off = 0;
    auto alloc = [&](size_t bytes) -> char* {
        char* r = p + off;
        off = (off + bytes + 255) & ~(size_t)255;
        return r;
    };
    const int NB256 = (NN + 255) / 256;          // 391
    int*   flag = (int*)  alloc(4);
    int*   cnt  = (int*)  alloc((size_t)NN * 4);
    int*   offs = (int*)  alloc(((size_t)NN + 1) * 4);
    int*   cur  = (int*)  alloc((size_t)NN * 4);
    int*   part = (int*)  alloc((size_t)NN * 4);
    int*   bsum = (int*)  alloc(512 * 4);
    int*   bpre = (int*)  alloc(512 * 4);
    float* dinv = (float*)alloc((size_t)NN * 4);
    int*   cs   = (int*)  alloc((size_t)(EE + NN) * 4);
    bf16*  WtL  = (bf16*) alloc((size_t)DD * DD * 2);
    bf16*  Wt1  = (bf16*) alloc((size_t)DD * DD * 2);
    bf16*  Wt2  = (bf16*) alloc((size_t)DD * DD * 2);
    const size_t NBH = (size_t)NN * DD * 2;      // 51.2 MB bf16 slab
    bf16*  S1   = (bf16*) alloc(NBH);
    bf16*  S2   = (bf16*) alloc(NBH);

    // --- CSR build ---
    (void)hipMemsetAsync(cnt, 0, (size_t)NN * 4, stream);
    count_deg_k<<<EE / 256, 256, 0, stream>>>(e_dst, cnt);
    scan_blk_k <<<NB256, 256, 0, stream>>>(cnt, part, bsum, dinv);
    scan_top_k <<<1, 512, 0, stream>>>(bsum, bpre, NB256);
    scan_fin_k <<<NB256, 256, 0, stream>>>(part, bpre, cnt, offs, cur, cs);
    fill_csr_k <<<NSUB * 8, 256, 0, stream>>>(e_src, e_dst, cur, cs);

    // --- weight transpose-cvt + mask probe ---
    prep_k<<<193, 256, 0, stream>>>(W_lin, W_g1, W_g2, WtL, Wt1, Wt2,
                                    (const unsigned int*)mask1, flag);

    // --- pipeline: GCNConv as dinv-scaled (A . X) . W ---
    const int GB = (NN + 127) / 128;   // 782 full-N blocks
    // h0 = dinv * dropout(relu(omega @ W_lin + b_lin))   omega(f32) -> S1
    gemm_k<0, 1, 1><<<GB, 512, 0, stream>>>(omega, WtL, b_lin, mask1, flag, nullptr, dinv, S1);
    // g1 = dinv * (A . h0)                               S1 -> S2
    agg_k<<<NN / 4, 256, 0, stream>>>(S1, offs, cs, dinv, S2);
    // h1 = dinv * dropout(relu(g1 @ W_g1 + b_g1))        S2 -> S1
    gemm_k<1, 1, 0><<<GB, 512, 0, stream>>>(S2, Wt1, b_g1, mask2, flag, nullptr, dinv, S1);
    // g2 = dinv * (A . h1)                               S1 -> S2
    agg_k<<<NN / 4, 256, 0, stream>>>(S1, offs, cs, dinv, S2);
    // out = z * (g2 @ W_g2 + b_g2)                       S2 -> d_out (fp32, nt)
    gemm_k<2, 2, 0><<<GB, 512, 0, stream>>>(S2, Wt2, b_g2, nullptr, flag, z, dinv, d_out);
}

// Round 13
// 619.362 us; speedup vs baseline: 1.0598x; 1.0598x over previous
//
#include <hip/hip_runtime.h>
#include <stdint.h>

#define NN 100000
#define EE 1600000
#define DD 256

typedef __bf16 bf16;
typedef __attribute__((ext_vector_type(8))) __bf16 bf16x8;
typedef __attribute__((ext_vector_type(4))) float f32x4;
typedef __attribute__((ext_vector_type(4))) unsigned int u32x4;
typedef __attribute__((ext_vector_type(8))) unsigned short u16x8;

typedef __attribute__((address_space(1))) const unsigned int g_u32c;
typedef __attribute__((address_space(3))) unsigned int lds_u32;

__device__ __forceinline__ float bflo(unsigned int u) {
    union { unsigned int u; float f; } x; x.u = u << 16; return x.f;
}
__device__ __forceinline__ float bfhi(unsigned int u) {
    union { unsigned int u; float f; } x; x.u = u & 0xFFFF0000u; return x.f;
}
__device__ __forceinline__ unsigned short f2bf(float f) {
    return __builtin_bit_cast(unsigned short, (__bf16)f);
}

// ---------------------------------------------------------------------------
// CSR build (cs only — edge weights folded into pre/post dinv scaling)
// ---------------------------------------------------------------------------
__global__ void count_deg_k(const int* __restrict__ dst, int* __restrict__ cnt) {
    int e = blockIdx.x * 256 + threadIdx.x;
    if (e < EE) atomicAdd(&cnt[dst[e]], 1);
}
__global__ __launch_bounds__(256) void scan_blk_k(const int* __restrict__ cnt,
                                                  int* __restrict__ part,
                                                  int* __restrict__ bsum,
                                                  float* __restrict__ dinv) {
    __shared__ int buf[256];
    int i = blockIdx.x * 256 + threadIdx.x;
    int v = 0;
    if (i < NN) { v = cnt[i] + 1; dinv[i] = rsqrtf((float)v); }   // +1 self-loop
    buf[threadIdx.x] = v;
    __syncthreads();
    for (int off = 1; off < 256; off <<= 1) {
        int t = (threadIdx.x >= off) ? buf[threadIdx.x - off] : 0;
        __syncthreads();
        buf[threadIdx.x] += t;
        __syncthreads();
    }
    if (i < NN) part[i] = buf[threadIdx.x];
    if (threadIdx.x == 255) bsum[blockIdx.x] = buf[255];
}
__global__ __launch_bounds__(512) void scan_top_k(const int* __restrict__ bsum,
                                                  int* __restrict__ bpre, int nb) {
    __shared__ int buf[512];
    int v = (threadIdx.x < (unsigned)nb) ? bsum[threadIdx.x] : 0;
    buf[threadIdx.x] = v;
    __syncthreads();
    for (int off = 1; off < 512; off <<= 1) {
        int t = (threadIdx.x >= off) ? buf[threadIdx.x - off] : 0;
        __syncthreads();
        buf[threadIdx.x] += t;
        __syncthreads();
    }
    if (threadIdx.x < (unsigned)nb) bpre[threadIdx.x] = buf[threadIdx.x] - v;
}
__global__ void scan_fin_k(const int* __restrict__ part, const int* __restrict__ bpre,
                           const int* __restrict__ cnt,
                           int* __restrict__ offs, int* __restrict__ cur,
                           int* __restrict__ cs) {
    int i = blockIdx.x * 256 + threadIdx.x;
    if (i >= NN) return;
    int o1 = part[i] + bpre[blockIdx.x];
    offs[i + 1] = o1;
    if (i == 0) offs[0] = 0;
    int o = o1 - (cnt[i] + 1);
    cs[o] = i;                 // self-loop (dinv^2 emerges from pre+post scaling)
    cur[i] = o + 1;
}
// Dst-partitioned fill (R11-proven): part p = bid&7 -> one XCD under round-robin
// dispatch; cs/cur lines of one dst-range written from one XCD's L2.
#define NSUB 128
__global__ __launch_bounds__(256) void fill_csr_k(
    const int* __restrict__ src, const int* __restrict__ dst,
    int* __restrict__ cur, int* __restrict__ cs) {
    int bid = blockIdx.x;
    int prt = bid & 7;
    int sub = bid >> 3;
    int lo = prt * (NN >> 3);
    int hi = (prt == 7) ? NN : lo + (NN >> 3);
    const int per = EE / NSUB;
    int e0 = sub * per;
    int e1 = (sub == NSUB - 1) ? EE : e0 + per;
    for (int e = e0 + threadIdx.x; e < e1; e += 256) {
        int d = dst[e];
        if (d >= lo && d < hi) {
            int s = src[e];
            int pos = atomicAdd(&cur[d], 1);
            cs[pos] = s;
        }
    }
}

// ---------------------------------------------------------------------------
// prep: Wt[n][k] = (bf16)W[k][n] for 3 weights (blocks 0..191) + mask probe (192)
// ---------------------------------------------------------------------------
__global__ __launch_bounds__(256) void prep_k(
    const float* __restrict__ W0, const float* __restrict__ W1, const float* __restrict__ W2,
    bf16* __restrict__ T0, bf16* __restrict__ T1, bf16* __restrict__ T2,
    const unsigned int* __restrict__ m, int* __restrict__ flag) {
    int b = blockIdx.x;
    if (b == 192) {
        if (threadIdx.x < 64) {
            unsigned int v = m[threadIdx.x];
            int bad = (v > 1u && v != 0x3F800000u) ? 1 : 0;
            unsigned long long bl = __ballot(bad);
            if (threadIdx.x == 0) *flag = (bl != 0ull) ? 1 : 0;
        }
        return;
    }
    const float* W = b < 64 ? W0 : (b < 128 ? W1 : W2);
    bf16*       T  = b < 64 ? T0 : (b < 128 ? T1 : T2);
    int bb = b & 63;
    __shared__ float tile[32][33];
    int bx = bb & 7, by = bb >> 3;
    int tx = threadIdx.x & 31, ty = threadIdx.x >> 5;
    #pragma unroll
    for (int r = 0; r < 32; r += 8)
        tile[ty + r][tx] = W[(size_t)(by * 32 + ty + r) * DD + bx * 32 + tx];
    __syncthreads();
    #pragma unroll
    for (int r = 0; r < 32; r += 8)
        T[(size_t)(bx * 32 + ty + r) * DD + by * 32 + tx] = (bf16)tile[tx][ty + r];
}

// ---------------------------------------------------------------------------
// bf16 MFMA GEMM (R11-proven skeleton): out[M,256] = A[M,256] @ W (Wt[n][k]).
// 128x128 tile, BK=64, 256 thr = 4 waves (2x2), linear LDS, global_load_lds,
// swapped-operand MFMA -> 4 consecutive output cols/lane -> vector epilogue.
// Grid 1568: m=((bid>>4)<<3)|(bid&7), h=(bid>>3)&1 (n-halves share XCD L2).
// F32A=1: A is fp32 (omega) — reg-staged cvt into As (fuses the cvt pass).
// EPI 1: +bias, relu, dropout(mask), *dinv[row] -> bf16.
// EPI 2: +bias, *z -> fp32 nt (final output).
// ---------------------------------------------------------------------------
template <int ID, int EPI, int F32A>
__global__ __launch_bounds__(256) void gemm_k(
    const void* __restrict__ Ap, const bf16* __restrict__ Wt,
    const float* __restrict__ bias, const void* __restrict__ mask,
    const int* __restrict__ flagp, const float* __restrict__ z,
    const float* __restrict__ dinv, void* __restrict__ outp) {
    __shared__ __align__(16) bf16 As[128 * 64];
    __shared__ __align__(16) bf16 Bs[128 * 64];

    int bid = blockIdx.x;
    int m   = ((bid >> 4) << 3) | (bid & 7);
    int h   = (bid >> 3) & 1;
    int m0  = m * 128, n0 = h * 128;
    if (m0 >= NN) return;
    int tid = threadIdx.x;
    int wid = tid >> 6, lane = tid & 63;
    int wm = wid >> 1, wn = wid & 1;
    int lr = lane & 15, lk = lane >> 4;

    f32x4 acc[4][4] = {};

    for (int k0 = 0; k0 < DD; k0 += 64) {
        #pragma unroll
        for (int i = 0; i < 4; i++) {
            int f = i * 256 + tid;            // 16B chunk id, 1024 per tile
            int row = f >> 3;
            int c   = (f & 7) * 8;
            int gr = m0 + row; if (gr > NN - 1) gr = NN - 1;
            if (F32A) {
                const float* sp = (const float*)Ap + (size_t)gr * DD + k0 + c;
                float4 v0 = *(const float4*)sp;
                float4 v1 = *(const float4*)(sp + 4);
                u16x8 o = { f2bf(v0.x), f2bf(v0.y), f2bf(v0.z), f2bf(v0.w),
                            f2bf(v1.x), f2bf(v1.y), f2bf(v1.z), f2bf(v1.w) };
                *(u16x8*)(As + row * 64 + c) = o;
            } else {
                __builtin_amdgcn_global_load_lds(
                    (g_u32c*)((const bf16*)Ap + (size_t)gr * DD + k0 + c),
                    (lds_u32*)(As + (size_t)f * 8), 16, 0, 0);
            }
            __builtin_amdgcn_global_load_lds(
                (g_u32c*)(Wt + (size_t)(n0 + row) * DD + k0 + c),
                (lds_u32*)(Bs + (size_t)f * 8), 16, 0, 0);
        }
        __syncthreads();
        #pragma unroll
        for (int kk = 0; kk < 2; kk++) {
            bf16x8 af[4], bfr[4];
            #pragma unroll
            for (int mi = 0; mi < 4; mi++)
                af[mi] = *(const bf16x8*)(As + (wm * 64 + mi * 16 + lr) * 64 + kk * 32 + lk * 8);
            #pragma unroll
            for (int ni = 0; ni < 4; ni++)
                bfr[ni] = *(const bf16x8*)(Bs + (wn * 64 + ni * 16 + lr) * 64 + kk * 32 + lk * 8);
            #pragma unroll
            for (int mi = 0; mi < 4; mi++)
                #pragma unroll
                for (int ni = 0; ni < 4; ni++)
                    acc[mi][ni] = __builtin_amdgcn_mfma_f32_16x16x32_bf16(
                        bfr[ni], af[mi], acc[mi][ni], 0, 0, 0);   // swapped
        }
        __syncthreads();
    }

    int bm = (EPI == 1) ? *flagp : 0;
    #pragma unroll
    for (int mi = 0; mi < 4; mi++) {
        int gr = m0 + wm * 64 + mi * 16 + lr;          // row = lane&15
        if (gr >= NN) continue;
        float ds = (EPI == 1) ? dinv[gr] : 0.f;        // pre-scale for agg input
        #pragma unroll
        for (int ni = 0; ni < 4; ni++) {
            int gc = n0 + wn * 64 + ni * 16 + lk * 4;  // 4 consecutive cols
            size_t idx = (size_t)gr * DD + gc;
            float4 b4 = *(const float4*)(bias + gc);
            float v0 = acc[mi][ni][0] + b4.x;
            float v1 = acc[mi][ni][1] + b4.y;
            float v2 = acc[mi][ni][2] + b4.z;
            float v3 = acc[mi][ni][3] + b4.w;
            if (EPI == 1) {
                v0 = fmaxf(v0, 0.f); v1 = fmaxf(v1, 0.f);
                v2 = fmaxf(v2, 0.f); v3 = fmaxf(v3, 0.f);
                if (bm) {
                    uchar4 u = *(const uchar4*)((const unsigned char*)mask + idx);
                    v0 *= u.x ? 2.f : 0.f; v1 *= u.y ? 2.f : 0.f;
                    v2 *= u.z ? 2.f : 0.f; v3 *= u.w ? 2.f : 0.f;
                } else {
                    uint4 u = *(const uint4*)((const unsigned int*)mask + idx);
                    v0 *= u.x ? 2.f : 0.f; v1 *= u.y ? 2.f : 0.f;
                    v2 *= u.z ? 2.f : 0.f; v3 *= u.w ? 2.f : 0.f;
                }
                v0 *= ds; v1 *= ds; v2 *= ds; v3 *= ds;
                ushort4 o = { f2bf(v0), f2bf(v1), f2bf(v2), f2bf(v3) };
                *(ushort4*)((unsigned short*)outp + idx) = o;
            } else {
                f32x4 zz = __builtin_nontemporal_load((const f32x4*)(z + idx));
                f32x4 o = { v0 * zz.x, v1 * zz.y, v2 * zz.z, v3 * zz.w };
                __builtin_nontemporal_store(o, (f32x4*)((float*)outp + idx));
            }
        }
    }
}

// ---------------------------------------------------------------------------
// CSR gather, unit weights (rows pre-scaled): out[n,:] = dinv[n] * sum rows.
// One wave per node; 32 lanes x 16B per row, 2 rows per step (half-split).
// Depth-4 load pipeline, named rotating registers, static indices.
// ---------------------------------------------------------------------------
#define AGG_GET(J, UVAR, MVAR)                                                   \
    {                                                                            \
        int _i = 2 * (J) + half;                                                 \
        int _s = __shfl(sl, _i & 63);                                            \
        MVAR = (_i < nume) ? 1.f : 0.f;                                          \
        UVAR = *(const u32x4*)(tb + (((size_t)(unsigned)_s) << 9) + lcoff);      \
    }
#define AGG_FMA(UVAR, MVAR)                                                      \
    {                                                                            \
        acc[0] = fmaf(MVAR, bflo(UVAR.x), acc[0]);                               \
        acc[1] = fmaf(MVAR, bfhi(UVAR.x), acc[1]);                               \
        acc[2] = fmaf(MVAR, bflo(UVAR.y), acc[2]);                               \
        acc[3] = fmaf(MVAR, bfhi(UVAR.y), acc[3]);                               \
        acc[4] = fmaf(MVAR, bflo(UVAR.z), acc[4]);                               \
        acc[5] = fmaf(MVAR, bfhi(UVAR.z), acc[5]);                               \
        acc[6] = fmaf(MVAR, bflo(UVAR.w), acc[6]);                               \
        acc[7] = fmaf(MVAR, bfhi(UVAR.w), acc[7]);                               \
    }

__global__ __launch_bounds__(256) void agg_k(
    const bf16* __restrict__ t, const int* __restrict__ offs,
    const int* __restrict__ cs, const float* __restrict__ dinv,
    bf16* __restrict__ out) {
    int node = blockIdx.x * 4 + (threadIdx.x >> 6);
    if (node >= NN) return;
    int lane = threadIdx.x & 63;
    int half = lane >> 5;
    int lc = lane & 31;
    int beg = offs[node], end = offs[node + 1];

    float acc[8] = {};
    const char* tb = (const char*)t;
    size_t lcoff = (size_t)(lc << 4);

    for (int base = beg; base < end; base += 64) {
        int nume = min(64, end - base);
        int sl = 0;
        if (lane < nume) sl = __builtin_nontemporal_load(cs + base + lane);
        int nit = (nume + 1) >> 1;

        u32x4 ua, ub, uc, ud;
        float ma, mb, mc, md;
        AGG_GET(0, ua, ma);
        AGG_GET(1, ub, mb);
        AGG_GET(2, uc, mc);
        int j = 0;
        for (; j + 3 < nit; j += 4) {
            AGG_GET(j + 3, ud, md); AGG_FMA(ua, ma);
            AGG_GET(j + 4, ua, ma); AGG_FMA(ub, mb);
            AGG_GET(j + 5, ub, mb); AGG_FMA(uc, mc);
            AGG_GET(j + 6, uc, mc); AGG_FMA(ud, md);
        }
        int rem = nit - j;
        if (rem > 0) AGG_FMA(ua, ma);
        if (rem > 1) AGG_FMA(ub, mb);
        if (rem > 2) AGG_FMA(uc, mc);
    }

    float dn = dinv[node];
    #pragma unroll
    for (int i = 0; i < 8; i++) {
        acc[i] += __shfl_xor(acc[i], 32);
        acc[i] *= dn;
    }
    if (half == 0) {
        u16x8 o = { f2bf(acc[0]), f2bf(acc[1]), f2bf(acc[2]), f2bf(acc[3]),
                    f2bf(acc[4]), f2bf(acc[5]), f2bf(acc[6]), f2bf(acc[7]) };
        __builtin_nontemporal_store(o, (u16x8*)((unsigned short*)out + (size_t)node * DD + lc * 8));
    }
}

// ---------------------------------------------------------------------------
extern "C" void kernel_launch(void* const* d_in, const int* in_sizes, int n_in,
                              void* d_out, int out_size, void* d_ws, size_t ws_size,
                              hipStream_t stream) {
    const float* z     = (const float*)d_in[0];
    const float* omega = (const float*)d_in[1];
    const int*   eidx  = (const int*)d_in[2];
    const float* W_lin = (const float*)d_in[3];
    const float* b_lin = (const float*)d_in[4];
    const float* W_g1  = (const float*)d_in[5];
    const float* b_g1  = (const float*)d_in[6];
    const float* W_g2  = (const float*)d_in[7];
    const float* b_g2  = (const float*)d_in[8];
    const void*  mask1 = d_in[9];
    const void*  mask2 = d_in[10];

    const int* e_src = eidx;
    const int* e_dst = eidx + EE;

    char* p = (char*)d_ws;
    size_t off = 0;
    auto alloc = [&](size_t bytes) -> char* {
        char* r = p + off;
        off = (off + bytes + 255) & ~(size_t)255;
        return r;
    };
    const int NB256 = (NN + 255) / 256;          // 391
    int*   flag = (int*)  alloc(4);
    int*   cnt  = (int*)  alloc((size_t)NN * 4);
    int*   offs = (int*)  alloc(((size_t)NN + 1) * 4);
    int*   cur  = (int*)  alloc((size_t)NN * 4);
    int*   part = (int*)  alloc((size_t)NN * 4);
    int*   bsum = (int*)  alloc(512 * 4);
    int*   bpre = (int*)  alloc(512 * 4);
    float* dinv = (float*)alloc((size_t)NN * 4);
    int*   cs   = (int*)  alloc((size_t)(EE + NN) * 4);
    bf16*  WtL  = (bf16*) alloc((size_t)DD * DD * 2);
    bf16*  Wt1  = (bf16*) alloc((size_t)DD * DD * 2);
    bf16*  Wt2  = (bf16*) alloc((size_t)DD * DD * 2);
    const size_t NBH = (size_t)NN * DD * 2;      // 51.2 MB bf16 slab
    bf16*  S1   = (bf16*) alloc(NBH);
    bf16*  S2   = (bf16*) alloc(NBH);

    // --- CSR build ---
    (void)hipMemsetAsync(cnt, 0, (size_t)NN * 4, stream);
    count_deg_k<<<EE / 256, 256, 0, stream>>>(e_dst, cnt);
    scan_blk_k <<<NB256, 256, 0, stream>>>(cnt, part, bsum, dinv);
    scan_top_k <<<1, 512, 0, stream>>>(bsum, bpre, NB256);
    scan_fin_k <<<NB256, 256, 0, stream>>>(part, bpre, cnt, offs, cur, cs);
    fill_csr_k <<<NSUB * 8, 256, 0, stream>>>(e_src, e_dst, cur, cs);

    // --- weight transpose-cvt + mask probe ---
    prep_k<<<193, 256, 0, stream>>>(W_lin, W_g1, W_g2, WtL, Wt1, Wt2,
                                    (const unsigned int*)mask1, flag);

    // --- pipeline: GCNConv as dinv-scaled (A . X) . W ---
    const int GG = 1568;   // 784 m-blocks x 2 n-halves, XCD-paired
    // h0 = dinv * dropout(relu(omega @ W_lin + b_lin))   omega(f32) -> S1
    gemm_k<0, 1, 1><<<GG, 256, 0, stream>>>(omega, WtL, b_lin, mask1, flag, nullptr, dinv, S1);
    // g1 = dinv * (A . h0)                               S1 -> S2
    agg_k<<<NN / 4, 256, 0, stream>>>(S1, offs, cs, dinv, S2);
    // h1 = dinv * dropout(relu(g1 @ W_g1 + b_g1))        S2 -> S1
    gemm_k<1, 1, 0><<<GG, 256, 0, stream>>>(S2, Wt1, b_g1, mask2, flag, nullptr, dinv, S1);
    // g2 = dinv * (A . h1)                               S1 -> S2
    agg_k<<<NN / 4, 256, 0, stream>>>(S1, offs, cs, dinv, S2);
    // out = z * (g2 @ W_g2 + b_g2)                       S2 -> d_out (fp32, nt)
    gemm_k<2, 2, 0><<<GG, 256, 0, stream>>>(S2, Wt2, b_g2, nullptr, flag, z, dinv, d_out);
}

// Round 14
// 611.268 us; speedup vs baseline: 1.0738x; 1.0132x over previous
//
#include <hip/hip_runtime.h>
#include <stdint.h>

#define NN 100000
#define EE 1600000
#define DD 256

typedef __bf16 bf16;
typedef __attribute__((ext_vector_type(8))) __bf16 bf16x8;
typedef __attribute__((ext_vector_type(4))) float f32x4;
typedef __attribute__((ext_vector_type(4))) unsigned int u32x4;
typedef __attribute__((ext_vector_type(8))) unsigned short u16x8;

typedef __attribute__((address_space(1))) const unsigned int g_u32c;
typedef __attribute__((address_space(3))) unsigned int lds_u32;

__device__ __forceinline__ float bflo(unsigned int u) {
    union { unsigned int u; float f; } x; x.u = u << 16; return x.f;
}
__device__ __forceinline__ float bfhi(unsigned int u) {
    union { unsigned int u; float f; } x; x.u = u & 0xFFFF0000u; return x.f;
}
__device__ __forceinline__ unsigned short f2bf(float f) {
    return __builtin_bit_cast(unsigned short, (__bf16)f);
}

// ---------------------------------------------------------------------------
// CSR build (cs only — edge weights folded into pre/post dinv scaling)
// ---------------------------------------------------------------------------
// Dst-partitioned (R11-proven on fill): part p = bid&7 -> one XCD under
// round-robin dispatch; cnt lines of one dst-range stay in one XCD's L2.
#define NSUB 128
__global__ __launch_bounds__(256) void count_deg_k(
    const int* __restrict__ dst, int* __restrict__ cnt) {
    int bid = blockIdx.x;
    int prt = bid & 7;
    int sub = bid >> 3;
    int lo = prt * (NN >> 3);
    int hi = (prt == 7) ? NN : lo + (NN >> 3);
    const int per = EE / NSUB;
    int e0 = sub * per;
    int e1 = (sub == NSUB - 1) ? EE : e0 + per;
    for (int e = e0 + threadIdx.x; e < e1; e += 256) {
        int d = dst[e];
        if (d >= lo && d < hi) atomicAdd(&cnt[d], 1);
    }
}
__global__ __launch_bounds__(256) void scan_blk_k(const int* __restrict__ cnt,
                                                  int* __restrict__ part,
                                                  int* __restrict__ bsum,
                                                  float* __restrict__ dinv) {
    __shared__ int buf[256];
    int i = blockIdx.x * 256 + threadIdx.x;
    int v = 0;
    if (i < NN) { v = cnt[i] + 1; dinv[i] = rsqrtf((float)v); }   // +1 self-loop
    buf[threadIdx.x] = v;
    __syncthreads();
    for (int off = 1; off < 256; off <<= 1) {
        int t = (threadIdx.x >= off) ? buf[threadIdx.x - off] : 0;
        __syncthreads();
        buf[threadIdx.x] += t;
        __syncthreads();
    }
    if (i < NN) part[i] = buf[threadIdx.x];
    if (threadIdx.x == 255) bsum[blockIdx.x] = buf[255];
}
__global__ __launch_bounds__(512) void scan_top_k(const int* __restrict__ bsum,
                                                  int* __restrict__ bpre, int nb) {
    __shared__ int buf[512];
    int v = (threadIdx.x < (unsigned)nb) ? bsum[threadIdx.x] : 0;
    buf[threadIdx.x] = v;
    __syncthreads();
    for (int off = 1; off < 512; off <<= 1) {
        int t = (threadIdx.x >= off) ? buf[threadIdx.x - off] : 0;
        __syncthreads();
        buf[threadIdx.x] += t;
        __syncthreads();
    }
    if (threadIdx.x < (unsigned)nb) bpre[threadIdx.x] = buf[threadIdx.x] - v;
}
__global__ void scan_fin_k(const int* __restrict__ part, const int* __restrict__ bpre,
                           const int* __restrict__ cnt,
                           int* __restrict__ offs, int* __restrict__ cur,
                           int* __restrict__ cs) {
    int i = blockIdx.x * 256 + threadIdx.x;
    if (i >= NN) return;
    int o1 = part[i] + bpre[blockIdx.x];
    offs[i + 1] = o1;
    if (i == 0) offs[0] = 0;
    int o = o1 - (cnt[i] + 1);
    cs[o] = i;                 // self-loop (dinv^2 emerges from pre+post scaling)
    cur[i] = o + 1;
}
__global__ __launch_bounds__(256) void fill_csr_k(
    const int* __restrict__ src, const int* __restrict__ dst,
    int* __restrict__ cur, int* __restrict__ cs) {
    int bid = blockIdx.x;
    int prt = bid & 7;
    int sub = bid >> 3;
    int lo = prt * (NN >> 3);
    int hi = (prt == 7) ? NN : lo + (NN >> 3);
    const int per = EE / NSUB;
    int e0 = sub * per;
    int e1 = (sub == NSUB - 1) ? EE : e0 + per;
    for (int e = e0 + threadIdx.x; e < e1; e += 256) {
        int d = dst[e];
        if (d >= lo && d < hi) {
            int s = src[e];
            int pos = atomicAdd(&cur[d], 1);
            cs[pos] = s;
        }
    }
}

// ---------------------------------------------------------------------------
// prep: Wt[n][k] = (bf16)W[k][n] for 3 weights (blocks 0..191) + mask probe (192)
// ---------------------------------------------------------------------------
__global__ __launch_bounds__(256) void prep_k(
    const float* __restrict__ W0, const float* __restrict__ W1, const float* __restrict__ W2,
    bf16* __restrict__ T0, bf16* __restrict__ T1, bf16* __restrict__ T2,
    const unsigned int* __restrict__ m, int* __restrict__ flag) {
    int b = blockIdx.x;
    if (b == 192) {
        if (threadIdx.x < 64) {
            unsigned int v = m[threadIdx.x];
            int bad = (v > 1u && v != 0x3F800000u) ? 1 : 0;
            unsigned long long bl = __ballot(bad);
            if (threadIdx.x == 0) *flag = (bl != 0ull) ? 1 : 0;
        }
        return;
    }
    const float* W = b < 64 ? W0 : (b < 128 ? W1 : W2);
    bf16*       T  = b < 64 ? T0 : (b < 128 ? T1 : T2);
    int bb = b & 63;
    __shared__ float tile[32][33];
    int bx = bb & 7, by = bb >> 3;
    int tx = threadIdx.x & 31, ty = threadIdx.x >> 5;
    #pragma unroll
    for (int r = 0; r < 32; r += 8)
        tile[ty + r][tx] = W[(size_t)(by * 32 + ty + r) * DD + bx * 32 + tx];
    __syncthreads();
    #pragma unroll
    for (int r = 0; r < 32; r += 8)
        T[(size_t)(bx * 32 + ty + r) * DD + by * 32 + tx] = (bf16)tile[tx][ty + r];
}

// ---------------------------------------------------------------------------
// bf16 MFMA GEMM, 64x256 tile (full-N -> A read once): out = A[M,256] @ W.
// Same skeleton as R11/R13 (256 thr, linear LDS, global_load_lds, 2 barriers
// per K-step, swapped-operand MFMA, vector epilogue); only the tile aspect
// changed (was 128x128 in 2 n-half blocks). 4 waves = 1m x 4n; per wave
// 4x4 frags (acc 64 VGPR, proven shape). LDS 40KB: As 64x64, Bs 256x64.
// F32A=1: A is fp32 (omega) — reg-staged cvt into As.
// EPI 1: +bias, relu, dropout(mask), *dinv[row] -> bf16.
// EPI 2: +bias, *z -> fp32 nt (final output).
// ---------------------------------------------------------------------------
template <int ID, int EPI, int F32A>
__global__ __launch_bounds__(256) void gemm_k(
    const void* __restrict__ Ap, const bf16* __restrict__ Wt,
    const float* __restrict__ bias, const void* __restrict__ mask,
    const int* __restrict__ flagp, const float* __restrict__ z,
    const float* __restrict__ dinv, void* __restrict__ outp) {
    __shared__ __align__(16) bf16 As[64 * 64];     // 8 KB
    __shared__ __align__(16) bf16 Bs[256 * 64];    // 32 KB

    int m0 = blockIdx.x * 64;
    if (m0 >= NN) return;
    int tid = threadIdx.x;
    int wid = tid >> 6, lane = tid & 63;
    int lr = lane & 15, lk = lane >> 4;

    f32x4 acc[4][4] = {};

    for (int k0 = 0; k0 < DD; k0 += 64) {
        // ---- stage A tile: 512 16B chunks / 256 thr = 2 per thread ----
        #pragma unroll
        for (int i = 0; i < 2; i++) {
            int f = i * 256 + tid;
            int row = f >> 3;
            int c   = (f & 7) * 8;
            int gr = m0 + row; if (gr > NN - 1) gr = NN - 1;
            if (F32A) {
                const float* sp = (const float*)Ap + (size_t)gr * DD + k0 + c;
                float4 v0 = *(const float4*)sp;
                float4 v1 = *(const float4*)(sp + 4);
                u16x8 o = { f2bf(v0.x), f2bf(v0.y), f2bf(v0.z), f2bf(v0.w),
                            f2bf(v1.x), f2bf(v1.y), f2bf(v1.z), f2bf(v1.w) };
                *(u16x8*)(As + row * 64 + c) = o;
            } else {
                __builtin_amdgcn_global_load_lds(
                    (g_u32c*)((const bf16*)Ap + (size_t)gr * DD + k0 + c),
                    (lds_u32*)(As + (size_t)f * 8), 16, 0, 0);
            }
        }
        // ---- stage B panel: 2048 chunks / 256 thr = 8 per thread ----
        #pragma unroll
        for (int i = 0; i < 8; i++) {
            int f = i * 256 + tid;
            int row = f >> 3;                 // n index 0..255
            int c   = (f & 7) * 8;
            __builtin_amdgcn_global_load_lds(
                (g_u32c*)(Wt + (size_t)row * DD + k0 + c),
                (lds_u32*)(Bs + (size_t)f * 8), 16, 0, 0);
        }
        __syncthreads();
        #pragma unroll
        for (int kk = 0; kk < 2; kk++) {
            bf16x8 af[4], bfr[4];
            #pragma unroll
            for (int mi = 0; mi < 4; mi++)
                af[mi] = *(const bf16x8*)(As + (mi * 16 + lr) * 64 + kk * 32 + lk * 8);
            #pragma unroll
            for (int ni = 0; ni < 4; ni++)
                bfr[ni] = *(const bf16x8*)(Bs + (wid * 64 + ni * 16 + lr) * 64 + kk * 32 + lk * 8);
            #pragma unroll
            for (int mi = 0; mi < 4; mi++)
                #pragma unroll
                for (int ni = 0; ni < 4; ni++)
                    acc[mi][ni] = __builtin_amdgcn_mfma_f32_16x16x32_bf16(
                        bfr[ni], af[mi], acc[mi][ni], 0, 0, 0);   // swapped
        }
        __syncthreads();
    }

    int bm = (EPI == 1) ? *flagp : 0;
    #pragma unroll
    for (int mi = 0; mi < 4; mi++) {
        int gr = m0 + mi * 16 + lr;                    // row = lane&15
        if (gr >= NN) continue;
        float ds = (EPI == 1) ? dinv[gr] : 0.f;        // pre-scale for agg input
        #pragma unroll
        for (int ni = 0; ni < 4; ni++) {
            int gc = wid * 64 + ni * 16 + lk * 4;      // 4 consecutive cols
            size_t idx = (size_t)gr * DD + gc;
            float4 b4 = *(const float4*)(bias + gc);
            float v0 = acc[mi][ni][0] + b4.x;
            float v1 = acc[mi][ni][1] + b4.y;
            float v2 = acc[mi][ni][2] + b4.z;
            float v3 = acc[mi][ni][3] + b4.w;
            if (EPI == 1) {
                v0 = fmaxf(v0, 0.f); v1 = fmaxf(v1, 0.f);
                v2 = fmaxf(v2, 0.f); v3 = fmaxf(v3, 0.f);
                if (bm) {
                    uchar4 u = *(const uchar4*)((const unsigned char*)mask + idx);
                    v0 *= u.x ? 2.f : 0.f; v1 *= u.y ? 2.f : 0.f;
                    v2 *= u.z ? 2.f : 0.f; v3 *= u.w ? 2.f : 0.f;
                } else {
                    uint4 u = *(const uint4*)((const unsigned int*)mask + idx);
                    v0 *= u.x ? 2.f : 0.f; v1 *= u.y ? 2.f : 0.f;
                    v2 *= u.z ? 2.f : 0.f; v3 *= u.w ? 2.f : 0.f;
                }
                v0 *= ds; v1 *= ds; v2 *= ds; v3 *= ds;
                ushort4 o = { f2bf(v0), f2bf(v1), f2bf(v2), f2bf(v3) };
                *(ushort4*)((unsigned short*)outp + idx) = o;
            } else {
                f32x4 zz = __builtin_nontemporal_load((const f32x4*)(z + idx));
                f32x4 o = { v0 * zz.x, v1 * zz.y, v2 * zz.z, v3 * zz.w };
                __builtin_nontemporal_store(o, (f32x4*)((float*)outp + idx));
            }
        }
    }
}

// ---------------------------------------------------------------------------
// CSR gather, unit weights (rows pre-scaled): out[n,:] = dinv[n] * sum rows.
// One wave per node; 32 lanes x 16B per row, 2 rows per step (half-split).
// Depth-4 load pipeline, named rotating registers, static indices.
// ---------------------------------------------------------------------------
#define AGG_GET(J, UVAR, MVAR)                                                   \
    {                                                                            \
        int _i = 2 * (J) + half;                                                 \
        int _s = __shfl(sl, _i & 63);                                            \
        MVAR = (_i < nume) ? 1.f : 0.f;                                          \
        UVAR = *(const u32x4*)(tb + (((size_t)(unsigned)_s) << 9) + lcoff);      \
    }
#define AGG_FMA(UVAR, MVAR)                                                      \
    {                                                                            \
        acc[0] = fmaf(MVAR, bflo(UVAR.x), acc[0]);                               \
        acc[1] = fmaf(MVAR, bfhi(UVAR.x), acc[1]);                               \
        acc[2] = fmaf(MVAR, bflo(UVAR.y), acc[2]);                               \
        acc[3] = fmaf(MVAR, bfhi(UVAR.y), acc[3]);                               \
        acc[4] = fmaf(MVAR, bflo(UVAR.z), acc[4]);                               \
        acc[5] = fmaf(MVAR, bfhi(UVAR.z), acc[5]);                               \
        acc[6] = fmaf(MVAR, bflo(UVAR.w), acc[6]);                               \
        acc[7] = fmaf(MVAR, bfhi(UVAR.w), acc[7]);                               \
    }

__global__ __launch_bounds__(256) void agg_k(
    const bf16* __restrict__ t, const int* __restrict__ offs,
    const int* __restrict__ cs, const float* __restrict__ dinv,
    bf16* __restrict__ out) {
    int node = blockIdx.x * 4 + (threadIdx.x >> 6);
    if (node >= NN) return;
    int lane = threadIdx.x & 63;
    int half = lane >> 5;
    int lc = lane & 31;
    int beg = offs[node], end = offs[node + 1];

    float acc[8] = {};
    const char* tb = (const char*)t;
    size_t lcoff = (size_t)(lc << 4);

    for (int base = beg; base < end; base += 64) {
        int nume = min(64, end - base);
        int sl = 0;
        if (lane < nume) sl = __builtin_nontemporal_load(cs + base + lane);
        int nit = (nume + 1) >> 1;

        u32x4 ua, ub, uc, ud;
        float ma, mb, mc, md;
        AGG_GET(0, ua, ma);
        AGG_GET(1, ub, mb);
        AGG_GET(2, uc, mc);
        int j = 0;
        for (; j + 3 < nit; j += 4) {
            AGG_GET(j + 3, ud, md); AGG_FMA(ua, ma);
            AGG_GET(j + 4, ua, ma); AGG_FMA(ub, mb);
            AGG_GET(j + 5, ub, mb); AGG_FMA(uc, mc);
            AGG_GET(j + 6, uc, mc); AGG_FMA(ud, md);
        }
        int rem = nit - j;
        if (rem > 0) AGG_FMA(ua, ma);
        if (rem > 1) AGG_FMA(ub, mb);
        if (rem > 2) AGG_FMA(uc, mc);
    }

    float dn = dinv[node];
    #pragma unroll
    for (int i = 0; i < 8; i++) {
        acc[i] += __shfl_xor(acc[i], 32);
        acc[i] *= dn;
    }
    if (half == 0) {
        u16x8 o = { f2bf(acc[0]), f2bf(acc[1]), f2bf(acc[2]), f2bf(acc[3]),
                    f2bf(acc[4]), f2bf(acc[5]), f2bf(acc[6]), f2bf(acc[7]) };
        __builtin_nontemporal_store(o, (u16x8*)((unsigned short*)out + (size_t)node * DD + lc * 8));
    }
}

// ---------------------------------------------------------------------------
extern "C" void kernel_launch(void* const* d_in, const int* in_sizes, int n_in,
                              void* d_out, int out_size, void* d_ws, size_t ws_size,
                              hipStream_t stream) {
    const float* z     = (const float*)d_in[0];
    const float* omega = (const float*)d_in[1];
    const int*   eidx  = (const int*)d_in[2];
    const float* W_lin = (const float*)d_in[3];
    const float* b_lin = (const float*)d_in[4];
    const float* W_g1  = (const float*)d_in[5];
    const float* b_g1  = (const float*)d_in[6];
    const float* W_g2  = (const float*)d_in[7];
    const float* b_g2  = (const float*)d_in[8];
    const void*  mask1 = d_in[9];
    const void*  mask2 = d_in[10];

    const int* e_src = eidx;
    const int* e_dst = eidx + EE;

    char* p = (char*)d_ws;
    size_t off = 0;
    auto alloc = [&](size_t bytes) -> char* {
        char* r = p + off;
        off = (off + bytes + 255) & ~(size_t)255;
        return r;
    };
    const int NB256 = (NN + 255) / 256;          // 391
    int*   flag = (int*)  alloc(4);
    int*   cnt  = (int*)  alloc((size_t)NN * 4);
    int*   offs = (int*)  alloc(((size_t)NN + 1) * 4);
    int*   cur  = (int*)  alloc((size_t)NN * 4);
    int*   part = (int*)  alloc((size_t)NN * 4);
    int*   bsum = (int*)  alloc(512 * 4);
    int*   bpre = (int*)  alloc(512 * 4);
    float* dinv = (float*)alloc((size_t)NN * 4);
    int*   cs   = (int*)  alloc((size_t)(EE + NN) * 4);
    bf16*  WtL  = (bf16*) alloc((size_t)DD * DD * 2);
    bf16*  Wt1  = (bf16*) alloc((size_t)DD * DD * 2);
    bf16*  Wt2  = (bf16*) alloc((size_t)DD * DD * 2);
    const size_t NBH = (size_t)NN * DD * 2;      // 51.2 MB bf16 slab
    bf16*  S1   = (bf16*) alloc(NBH);
    bf16*  S2   = (bf16*) alloc(NBH);

    // --- CSR build ---
    (void)hipMemsetAsync(cnt, 0, (size_t)NN * 4, stream);
    count_deg_k<<<NSUB * 8, 256, 0, stream>>>(e_dst, cnt);
    scan_blk_k <<<NB256, 256, 0, stream>>>(cnt, part, bsum, dinv);
    scan_top_k <<<1, 512, 0, stream>>>(bsum, bpre, NB256);
    scan_fin_k <<<NB256, 256, 0, stream>>>(part, bpre, cnt, offs, cur, cs);
    fill_csr_k <<<NSUB * 8, 256, 0, stream>>>(e_src, e_dst, cur, cs);

    // --- weight transpose-cvt + mask probe ---
    prep_k<<<193, 256, 0, stream>>>(W_lin, W_g1, W_g2, WtL, Wt1, Wt2,
                                    (const unsigned int*)mask1, flag);

    // --- pipeline: GCNConv as dinv-scaled (A . X) . W ---
    const int GB = (NN + 63) / 64;   // 1563 full-N blocks
    // h0 = dinv * dropout(relu(omega @ W_lin + b_lin))   omega(f32) -> S1
    gemm_k<0, 1, 1><<<GB, 256, 0, stream>>>(omega, WtL, b_lin, mask1, flag, nullptr, dinv, S1);
    // g1 = dinv * (A . h0)                               S1 -> S2
    agg_k<<<NN / 4, 256, 0, stream>>>(S1, offs, cs, dinv, S2);
    // h1 = dinv * dropout(relu(g1 @ W_g1 + b_g1))        S2 -> S1
    gemm_k<1, 1, 0><<<GB, 256, 0, stream>>>(S2, Wt1, b_g1, mask2, flag, nullptr, dinv, S1);
    // g2 = dinv * (A . h1)                               S1 -> S2
    agg_k<<<NN / 4, 256, 0, stream>>>(S1, offs, cs, dinv, S2);
    // out = z * (g2 @ W_g2 + b_g2)                       S2 -> d_out (fp32, nt)
    gemm_k<2, 2, 0><<<GB, 256, 0, stream>>>(S2, Wt2, b_g2, nullptr, flag, z, dinv, d_out);
}